// Round 10
// baseline (826.075 us; speedup 1.0000x reference)
//
#include <hip/hip_runtime.h>
#include <hip/hip_bf16.h>
#include <math.h>

#define BB 8
#define DD 256
#define LL 2048
#define KK 24
#define RR 1025
#define HH 512

// ---------------- LayerNorm over channel dim D, per (b,l) ----------------
__global__ void ln_kernel(const float* __restrict__ x, const float* __restrict__ gamma,
                          const float* __restrict__ beta, float* __restrict__ z) {
  __shared__ float red[2][4][64];
  __shared__ float mu_s[64], rs_s[64];
  int blk = blockIdx.x;
  int b = blk >> 5;            // / (L/64 = 32)
  int l0 = (blk & 31) << 6;
  int t = threadIdx.x;
  int ll = t & 63;
  int part = t >> 6;           // 0..3, each covers 64 d's
  int l = l0 + ll;
  const float* xb = x + ((size_t)b * DD) * LL + l;
  float xv[64];
  float s = 0.f, ss = 0.f;
  #pragma unroll
  for (int i = 0; i < 64; ++i) {
    float v = xb[(size_t)(part * 64 + i) * LL];
    xv[i] = v; s += v; ss += v * v;
  }
  red[0][part][ll] = s; red[1][part][ll] = ss;
  __syncthreads();
  if (part == 0) {
    float S = red[0][0][ll] + red[0][1][ll] + red[0][2][ll] + red[0][3][ll];
    float Q = red[1][0][ll] + red[1][1][ll] + red[1][2][ll] + red[1][3][ll];
    float mu = S * (1.f / 256.f);
    float var = Q * (1.f / 256.f) - mu * mu;
    mu_s[ll] = mu; rs_s[ll] = rsqrtf(var + 1e-5f);
  }
  __syncthreads();
  float mu = mu_s[ll], rs = rs_s[ll];
  float* zb = z + ((size_t)b * DD) * LL + l;
  #pragma unroll
  for (int i = 0; i < 64; ++i) {
    int d = part * 64 + i;
    zb[(size_t)d * LL] = (xv[i] - mu) * rs * gamma[d] + beta[d];
  }
}

// ---------------- generic 32x32 tiled transpose, batched ----------------
__global__ void transpose_kernel(const float* __restrict__ src, float* __restrict__ dst,
                                 int rows, int cols) {
  __shared__ float tile[32][33];
  int mat = blockIdx.z;
  const float* s = src + (size_t)mat * rows * cols;
  float* d = dst + (size_t)mat * rows * cols;
  int c0 = blockIdx.x * 32, r0 = blockIdx.y * 32;
  for (int i = threadIdx.y; i < 32; i += 8)
    tile[i][threadIdx.x] = s[(size_t)(r0 + i) * cols + c0 + threadIdx.x];
  __syncthreads();
  for (int i = threadIdx.y; i < 32; i += 8)
    d[(size_t)(c0 + i) * rows + r0 + threadIdx.x] = tile[threadIdx.x][i];
}

// ---------------- Stockham radix-2 FFT, n=2048, in LDS ----------------
__device__ __forceinline__ float2* fft2048(float2* bufA, float2* bufB,
                                           const float2* __restrict__ tw, int t) {
  float2* src = bufA; float2* dst = bufB;
  for (int stage = 0; stage < 11; ++stage) {
    int s = 1 << stage;
    #pragma unroll
    for (int j = 0; j < 4; ++j) {
      int idx = t + 256 * j;           // 0..1023
      int q = idx & (s - 1);
      int p = idx >> stage;
      float2 a = src[idx];
      float2 b = src[idx + 1024];
      float sr = a.x + b.x, si = a.y + b.y;
      float dr = a.x - b.x, di = a.y - b.y;
      float2 w = tw[p << stage];       // (cos, -sin)
      dst[q + 2 * s * p] = make_float2(sr, si);
      dst[q + 2 * s * p + s] = make_float2(dr * w.x - di * w.y, dr * w.y + di * w.x);
    }
    __syncthreads();
    float2* tmp = src; src = dst; dst = tmp;
  }
  return src;
}

__device__ __forceinline__ void build_tw(float2* tw, int t) {
  #pragma unroll
  for (int j = 0; j < 4; ++j) {
    int i = t + 256 * j;
    float xfrac = (float)i * (1.f / 1024.f);
    tw[i] = make_float2(cospif(xfrac), -sinpif(xfrac));
  }
}

__global__ void rfft_kernel(const float* __restrict__ z, float2* __restrict__ Xf) {
  __shared__ float2 bufA[2048];
  __shared__ float2 bufB[2048];
  __shared__ float2 tw[1024];
  int row = blockIdx.x;            // b*D + d
  int t = threadIdx.x;
  build_tw(tw, t);
  const float* zr = z + (size_t)row * LL;
  #pragma unroll
  for (int j = 0; j < 8; ++j) {
    int i = t + 256 * j;
    bufA[i] = make_float2(zr[i], 0.f);
  }
  __syncthreads();
  float2* res = fft2048(bufA, bufB, tw, t);
  #pragma unroll
  for (int j = 0; j < 5; ++j) {
    int r = t + 256 * j;
    if (r <= 1024) Xf[(size_t)row * RR + r] = res[r];
  }
}

// irfft(F, n=2048) = real( fft( conj(F_full) ) ) / 2048
__global__ void irfft_kernel(const float2* __restrict__ Sf, float* __restrict__ S) {
  __shared__ float2 bufA[2048];
  __shared__ float2 bufB[2048];
  __shared__ float2 tw[1024];
  int row = blockIdx.x;            // b*D + h
  int t = threadIdx.x;
  build_tw(tw, t);
  const float2* fr = Sf + (size_t)row * RR;
  #pragma unroll
  for (int j = 0; j < 8; ++j) {
    int i = t + 256 * j;
    float2 v;
    if (i <= 1024) { v = fr[i]; v.y = -v.y; }   // conj(F[i])
    else           { v = fr[2048 - i]; }        // F[2048-i]
    bufA[i] = v;
  }
  __syncthreads();
  float2* res = fft2048(bufA, bufB, tw, t);
  const float scale = 1.f / 2048.f;
  float* sr = S + (size_t)row * LL;
  #pragma unroll
  for (int j = 0; j < 8; ++j) {
    int i = t + 256 * j;
    sr[i] = res[i].x * scale;
  }
}

// ---------------- spectral mixing ----------------
// Sf[b,h,r] = sum_d Xf[b,d,r] * M[d,h,r],  M = sum_k Theta[k,h,d]*conj(Phi)[k,r]
// Block: 256 thr = 4 waves; wave kp owns k-chunk [6kp, 6kp+6).
// Lane (rl, hg): 1 r, 4 h (float4 Theta loads), all 8 b — same as round 6,
// but per-wave Theta loads per d = 6 (not 24). Total loads/block unchanged;
// waves x4. Deterministic 4-way LDS reduction (stride-33 pad, 2-way banks).
__global__ void __launch_bounds__(256)
spectral_kernel(const float2* __restrict__ Xf,
                const float* __restrict__ ThT,   // [K][d][h]
                const float* __restrict__ Phi_re,
                const float* __restrict__ Phi_im,
                float2* __restrict__ Sf) {
  __shared__ float2 xs[BB][32][8];     // 16 KB
  __shared__ float red[4 * 64 * 33];   // 33 KB, padded stride 33
  int t = threadIdx.x;                 // 0..255
  int rl = t & 7;
  int hg = (t >> 3) & 7;               // 0..7
  int kp = t >> 6;                     // 0..3 (wave id)
  int slot = t & 63;                   // (hg<<3)+rl
  int r0 = blockIdx.x << 3;
  int h = (blockIdx.y << 5) + (hg << 2);
  int r = r0 + rl;
  int rc = min(r, RR - 1);
  const float4* Tb = reinterpret_cast<const float4*>(ThT + h);  // +k*16384 +d*64

  float phr[6], phim[6];
  #pragma unroll
  for (int j = 0; j < 6; ++j) {
    int k = kp * 6 + j;
    phr[j]  = Phi_re[k * RR + rc];
    phim[j] = Phi_im[k * RR + rc];
  }
  float acr[4][BB], aci[4][BB];
  #pragma unroll
  for (int j = 0; j < 4; ++j)
    #pragma unroll
    for (int b = 0; b < BB; ++b) { acr[j][b] = 0.f; aci[j][b] = 0.f; }

  for (int wX = 0; wX < 8; ++wX) {
    int dcX = wX << 5;                 // 32-d window
    __syncthreads();
    #pragma unroll
    for (int jj = 0; jj < 8; ++jj) {
      int i = t + 256 * jj;            // 0..2047
      int b = i >> 8;
      int dl = (i >> 3) & 31;
      int rr = i & 7;
      xs[b][dl][rr] = Xf[((size_t)(b * DD + dcX + dl)) * RR + min(r0 + rr, RR - 1)];
    }
    __syncthreads();
    for (int dl = 0; dl < 32; ++dl) {
      int d = dcX + dl;
      const float4* tp = Tb + (size_t)d * 64 + (size_t)(kp * 6) * 16384;
      float4 th[6];
      #pragma unroll
      for (int j = 0; j < 6; ++j) th[j] = tp[(size_t)j * 16384];
      float mre[4] = {0.f, 0.f, 0.f, 0.f};
      float mim[4] = {0.f, 0.f, 0.f, 0.f};
      #pragma unroll
      for (int j = 0; j < 6; ++j) {
        float pr = phr[j], pi = phim[j];
        mre[0] += th[j].x * pr;  mim[0] -= th[j].x * pi;
        mre[1] += th[j].y * pr;  mim[1] -= th[j].y * pi;
        mre[2] += th[j].z * pr;  mim[2] -= th[j].z * pi;
        mre[3] += th[j].w * pr;  mim[3] -= th[j].w * pi;
      }
      #pragma unroll
      for (int b = 0; b < BB; ++b) {
        float2 xv = xs[b][dl][rl];
        #pragma unroll
        for (int j = 0; j < 4; ++j) {
          acr[j][b] += xv.x * mre[j] - xv.y * mim[j];
          aci[j][b] += xv.x * mim[j] + xv.y * mre[j];
        }
      }
    }
  }

  // ---- deterministic 4-way k-chunk reduction via padded LDS ----
  float sre[4][BB];
  // pass 1: real
  __syncthreads();
  {
    float* wp = &red[(kp * 64 + slot) * 33];
    #pragma unroll
    for (int j = 0; j < 4; ++j)
      #pragma unroll
      for (int b = 0; b < BB; ++b) wp[(j << 3) + b] = acr[j][b];
  }
  __syncthreads();
  if (kp == 0) {
    #pragma unroll
    for (int j = 0; j < 4; ++j)
      #pragma unroll
      for (int b = 0; b < BB; ++b) {
        int v = (j << 3) + b;
        sre[j][b] = red[slot * 33 + v] + red[(64 + slot) * 33 + v]
                  + red[(128 + slot) * 33 + v] + red[(192 + slot) * 33 + v];
      }
  }
  // pass 2: imag
  __syncthreads();
  {
    float* wp = &red[(kp * 64 + slot) * 33];
    #pragma unroll
    for (int j = 0; j < 4; ++j)
      #pragma unroll
      for (int b = 0; b < BB; ++b) wp[(j << 3) + b] = aci[j][b];
  }
  __syncthreads();
  if (kp == 0 && r < RR) {
    #pragma unroll
    for (int j = 0; j < 4; ++j)
      #pragma unroll
      for (int b = 0; b < BB; ++b) {
        int v = (j << 3) + b;
        float sim = red[slot * 33 + v] + red[(64 + slot) * 33 + v]
                  + red[(128 + slot) * 33 + v] + red[(192 + slot) * 33 + v];
        Sf[((size_t)(b * DD + h + j)) * RR + r] = make_float2(sre[j][b], sim);
      }
  }
}

// ---------------- fused MLP + residual, f32 output ----------------
__global__ void mlp_kernel(const float* __restrict__ S, const float* __restrict__ x,
                           const float* __restrict__ W1T, const float* __restrict__ b1,
                           const float* __restrict__ W2T, const float* __restrict__ b2,
                           float* __restrict__ out) {
  __shared__ float s_s[DD][32];
  __shared__ float h_s[128][36];
  int b = blockIdx.y;
  int l0 = blockIdx.x << 5;
  int t = threadIdx.x;
  {
    const float* Sp = S + ((size_t)(b * DD + t)) * LL + l0;
    float4* drow = reinterpret_cast<float4*>(&s_s[t][0]);
    const float4* srow = reinterpret_cast<const float4*>(Sp);
    #pragma unroll
    for (int j = 0; j < 8; ++j) drow[j] = srow[j];
  }
  int h_loc = t >> 1;
  int lhalf = t & 1;
  float acc[32];
  #pragma unroll
  for (int i = 0; i < 32; ++i) acc[i] = 0.f;

  for (int hcBase = 0; hcBase < HH; hcBase += 128) {
    __syncthreads();
    int h = hcBase + h_loc;
    float a[16];
    float bias = b1[h];
    #pragma unroll
    for (int i = 0; i < 16; ++i) a[i] = bias;
    for (int c = 0; c < DD; ++c) {
      float w = W1T[(size_t)c * HH + h];
      const float4* sv4 = reinterpret_cast<const float4*>(&s_s[c][lhalf * 16]);
      #pragma unroll
      for (int j = 0; j < 4; ++j) {
        float4 sv = sv4[j];
        a[j * 4 + 0] += w * sv.x; a[j * 4 + 1] += w * sv.y;
        a[j * 4 + 2] += w * sv.z; a[j * 4 + 3] += w * sv.w;
      }
    }
    #pragma unroll
    for (int i = 0; i < 16; ++i) {
      float v = a[i];
      h_s[h_loc][lhalf * 16 + i] = 0.5f * v * (1.f + erff(v * 0.70710678118654752f));
    }
    __syncthreads();
    for (int hh = 0; hh < 128; ++hh) {
      float w = W2T[(size_t)(hcBase + hh) * DD + t];
      const float4* hv4 = reinterpret_cast<const float4*>(&h_s[hh][0]);
      #pragma unroll
      for (int j = 0; j < 8; ++j) {
        float4 hv = hv4[j];
        acc[j * 4 + 0] += w * hv.x; acc[j * 4 + 1] += w * hv.y;
        acc[j * 4 + 2] += w * hv.z; acc[j * 4 + 3] += w * hv.w;
      }
    }
  }
  const float* xp = x + ((size_t)(b * DD + t)) * LL + l0;
  float* op = out + ((size_t)(b * DD + t)) * LL + l0;
  float bb2 = b2[t];
  #pragma unroll
  for (int j = 0; j < 8; ++j) {
    float4 xv = reinterpret_cast<const float4*>(xp)[j];
    float4 o;
    o.x = xv.x + bb2 + acc[j * 4 + 0];
    o.y = xv.y + bb2 + acc[j * 4 + 1];
    o.z = xv.z + bb2 + acc[j * 4 + 2];
    o.w = xv.w + bb2 + acc[j * 4 + 3];
    reinterpret_cast<float4*>(op)[j] = o;
  }
}

extern "C" void kernel_launch(void* const* d_in, const int* in_sizes, int n_in,
                              void* d_out, int out_size, void* d_ws, size_t ws_size,
                              hipStream_t stream) {
  const float* x      = (const float*)d_in[0];
  const float* Phi_re = (const float*)d_in[1];
  const float* Phi_im = (const float*)d_in[2];
  const float* Theta  = (const float*)d_in[3];
  const float* gamma  = (const float*)d_in[4];
  const float* beta   = (const float*)d_in[5];
  const float* W1     = (const float*)d_in[6];
  const float* b1     = (const float*)d_in[7];
  const float* W2     = (const float*)d_in[8];
  const float* b2     = (const float*)d_in[9];

  float* ws = (float*)d_ws;
  float*  z   = ws;                          // 4,194,304 floats (reused for S)
  float2* Xf  = (float2*)(ws + 4194304);     // 2,099,200 float2
  float2* Sf  = (float2*)(ws + 8392704);     // 2,099,200 float2
  float*  ThT = ws + 12591104;               // 1,572,864
  float*  W1T = ws + 14163968;               // 131,072
  float*  W2T = ws + 14295040;               // 131,072

  ln_kernel<<<dim3(BB * (LL / 64)), 256, 0, stream>>>(x, gamma, beta, z);
  transpose_kernel<<<dim3(8, 8, 24), dim3(32, 8), 0, stream>>>(Theta, ThT, 256, 256);
  transpose_kernel<<<dim3(8, 16, 1), dim3(32, 8), 0, stream>>>(W1, W1T, 512, 256);
  transpose_kernel<<<dim3(16, 8, 1), dim3(32, 8), 0, stream>>>(W2, W2T, 256, 512);
  rfft_kernel<<<dim3(BB * DD), 256, 0, stream>>>(z, Xf);
  spectral_kernel<<<dim3(129, 8), 256, 0, stream>>>(Xf, ThT, Phi_re, Phi_im, Sf);
  irfft_kernel<<<dim3(BB * DD), 256, 0, stream>>>(Sf, z);      // S -> z buffer
  mlp_kernel<<<dim3(LL / 32, BB), 256, 0, stream>>>(z, x, W1T, b1, W2T, b2,
                                                    (float*)d_out);
}

// Round 11
// 472.208 us; speedup vs baseline: 1.7494x; 1.7494x over previous
//
#include <hip/hip_runtime.h>
#include <hip/hip_bf16.h>
#include <hip/hip_fp16.h>
#include <math.h>

#define BB 8
#define DD 256
#define LL 2048
#define KK 24
#define RR 1025
#define HH 512

typedef __attribute__((ext_vector_type(8))) _Float16 f16x8;
typedef __attribute__((ext_vector_type(4))) float f32x4;

// ---------------- LayerNorm over channel dim D, per (b,l) ----------------
__global__ void ln_kernel(const float* __restrict__ x, const float* __restrict__ gamma,
                          const float* __restrict__ beta, float* __restrict__ z) {
  __shared__ float red[2][4][64];
  __shared__ float mu_s[64], rs_s[64];
  int blk = blockIdx.x;
  int b = blk >> 5;
  int l0 = (blk & 31) << 6;
  int t = threadIdx.x;
  int ll = t & 63;
  int part = t >> 6;
  int l = l0 + ll;
  const float* xb = x + ((size_t)b * DD) * LL + l;
  float xv[64];
  float s = 0.f, ss = 0.f;
  #pragma unroll
  for (int i = 0; i < 64; ++i) {
    float v = xb[(size_t)(part * 64 + i) * LL];
    xv[i] = v; s += v; ss += v * v;
  }
  red[0][part][ll] = s; red[1][part][ll] = ss;
  __syncthreads();
  if (part == 0) {
    float S = red[0][0][ll] + red[0][1][ll] + red[0][2][ll] + red[0][3][ll];
    float Q = red[1][0][ll] + red[1][1][ll] + red[1][2][ll] + red[1][3][ll];
    float mu = S * (1.f / 256.f);
    float var = Q * (1.f / 256.f) - mu * mu;
    mu_s[ll] = mu; rs_s[ll] = rsqrtf(var + 1e-5f);
  }
  __syncthreads();
  float mu = mu_s[ll], rs = rs_s[ll];
  float* zb = z + ((size_t)b * DD) * LL + l;
  #pragma unroll
  for (int i = 0; i < 64; ++i) {
    int d = part * 64 + i;
    zb[(size_t)d * LL] = (xv[i] - mu) * rs * gamma[d] + beta[d];
  }
}

// ---------------- generic 32x32 tiled transpose ----------------
__global__ void transpose_kernel(const float* __restrict__ src, float* __restrict__ dst,
                                 int rows, int cols) {
  __shared__ float tile[32][33];
  int mat = blockIdx.z;
  const float* s = src + (size_t)mat * rows * cols;
  float* d = dst + (size_t)mat * rows * cols;
  int c0 = blockIdx.x * 32, r0 = blockIdx.y * 32;
  for (int i = threadIdx.y; i < 32; i += 8)
    tile[i][threadIdx.x] = s[(size_t)(r0 + i) * cols + c0 + threadIdx.x];
  __syncthreads();
  for (int i = threadIdx.y; i < 32; i += 8)
    d[(size_t)(c0 + i) * rows + r0 + threadIdx.x] = tile[threadIdx.x][i];
}

// ---------------- Theta -> f16 A2[h][k*256+d] ----------------
__global__ void theta_prep(const float* __restrict__ Theta, unsigned* __restrict__ A2u) {
  int bi = blockIdx.x;
  int k = bi >> 8, h = bi & 255;
  int t = threadIdx.x;   // 0..127, d = 2t
  float2 v = *reinterpret_cast<const float2*>(Theta + (size_t)k * 65536 + h * 256 + 2 * t);
  A2u[(size_t)h * 3072 + k * 128 + t] =
      __builtin_bit_cast(unsigned, __floats2half2_rn(v.x, v.y));
}

// ---------------- Stockham radix-2 FFT, n=2048, in LDS ----------------
__device__ __forceinline__ float2* fft2048(float2* bufA, float2* bufB,
                                           const float2* __restrict__ tw, int t) {
  float2* src = bufA; float2* dst = bufB;
  for (int stage = 0; stage < 11; ++stage) {
    int s = 1 << stage;
    #pragma unroll
    for (int j = 0; j < 4; ++j) {
      int idx = t + 256 * j;
      int q = idx & (s - 1);
      int p = idx >> stage;
      float2 a = src[idx];
      float2 b = src[idx + 1024];
      float sr = a.x + b.x, si = a.y + b.y;
      float dr = a.x - b.x, di = a.y - b.y;
      float2 w = tw[p << stage];
      dst[q + 2 * s * p] = make_float2(sr, si);
      dst[q + 2 * s * p + s] = make_float2(dr * w.x - di * w.y, dr * w.y + di * w.x);
    }
    __syncthreads();
    float2* tmp = src; src = dst; dst = tmp;
  }
  return src;
}

__device__ __forceinline__ void build_tw(float2* tw, int t) {
  #pragma unroll
  for (int j = 0; j < 4; ++j) {
    int i = t + 256 * j;
    float xfrac = (float)i * (1.f / 1024.f);
    tw[i] = make_float2(cospif(xfrac), -sinpif(xfrac));
  }
}

// rfft -> packed f16 (re,im) per bin
__global__ void rfft_kernel(const float* __restrict__ z, unsigned* __restrict__ Xf2) {
  __shared__ float2 bufA[2048];
  __shared__ float2 bufB[2048];
  __shared__ float2 tw[1024];
  int row = blockIdx.x;
  int t = threadIdx.x;
  build_tw(tw, t);
  const float* zr = z + (size_t)row * LL;
  #pragma unroll
  for (int j = 0; j < 8; ++j) {
    int i = t + 256 * j;
    bufA[i] = make_float2(zr[i], 0.f);
  }
  __syncthreads();
  float2* res = fft2048(bufA, bufB, tw, t);
  #pragma unroll
  for (int j = 0; j < 5; ++j) {
    int r = t + 256 * j;
    if (r <= 1024) {
      float2 v = res[r];
      Xf2[(size_t)row * RR + r] = __builtin_bit_cast(unsigned, __floats2half2_rn(v.x, v.y));
    }
  }
}

// irfft(F, n=2048) = real( fft( conj(F_full) ) ) / 2048
__global__ void irfft_kernel(const float2* __restrict__ Sf, float* __restrict__ S) {
  __shared__ float2 bufA[2048];
  __shared__ float2 bufB[2048];
  __shared__ float2 tw[1024];
  int row = blockIdx.x;
  int t = threadIdx.x;
  build_tw(tw, t);
  const float2* fr = Sf + (size_t)row * RR;
  #pragma unroll
  for (int j = 0; j < 8; ++j) {
    int i = t + 256 * j;
    float2 v;
    if (i <= 1024) { v = fr[i]; v.y = -v.y; }
    else           { v = fr[2048 - i]; }
    bufA[i] = v;
  }
  __syncthreads();
  float2* res = fft2048(bufA, bufB, tw, t);
  const float scale = 1.f / 2048.f;
  float* sr = S + (size_t)row * LL;
  #pragma unroll
  for (int j = 0; j < 8; ++j) {
    int i = t + 256 * j;
    sr[i] = res[i].x * scale;
  }
}

// ---------------- spectral mixing as f16 MFMA GEMM ----------------
// Sf[h,(b,r,ri)] = sum_{kd} A2[h][kd] * B[kd][(r_l,b,ri)]
// kd = k*256+d (K=6144); B built on the fly: re = xr*pr + xi*pi,
// im = xi*pr - xr*pi (phic = pr - i*pi), packed f16 d-pairs.
// Grid (257 r-tiles of 4, 2 M-halves of 128); 256 thr = 4 waves;
// wave = 32 M x 64 N; 16x16x32 f16 MFMA, fragment recipe per m92/m97.
#define SPEC_BUILD(kk, dss, bbuf)                                              \
  {                                                                            \
    int d2l_ = t & 15;                                                         \
    int pp_ = t >> 4;                                                          \
    _Pragma("unroll")                                                          \
    for (int j_ = 0; j_ < 2; ++j_) {                                           \
      int p_ = pp_ + 16 * j_;                                                  \
      int rl_ = p_ >> 3, bb_ = p_ & 7;                                         \
      unsigned xr_ = xs_r[(dss) * 16 + d2l_][rl_][bb_];                        \
      unsigned xi_ = xs_i[(dss) * 16 + d2l_][rl_][bb_];                        \
      __half2 pr_ = __builtin_bit_cast(__half2, phi_pr[kk][rl_]);              \
      __half2 pi_ = __builtin_bit_cast(__half2, phi_pi[kk][rl_]);              \
      __half2 xrh_ = __builtin_bit_cast(__half2, xr_);                         \
      __half2 xih_ = __builtin_bit_cast(__half2, xi_);                         \
      __half2 re_ = __hfma2(xrh_, pr_, __hmul2(xih_, pi_));                    \
      __half2 im_ = __hfma2(xih_, pr_, __hneg2(__hmul2(xrh_, pi_)));           \
      Bl[bbuf][2 * p_][d2l_] = __builtin_bit_cast(unsigned, re_);              \
      Bl[bbuf][2 * p_ + 1][d2l_] = __builtin_bit_cast(unsigned, im_);          \
    }                                                                          \
  }

__global__ void __launch_bounds__(256)
spectral_mfma(const unsigned* __restrict__ Xf2,        // [(b*256+d)][1025] half2
              const unsigned short* __restrict__ A2,   // [h][6144] f16
              const float* __restrict__ Phi_re,
              const float* __restrict__ Phi_im,
              float2* __restrict__ Sf) {
  __shared__ unsigned xs_r[32][4][8];            // 4 KB  (d2, r_l, b)
  __shared__ unsigned xs_i[32][4][8];            // 4 KB
  __shared__ alignas(16) unsigned Bl[2][64][20]; // 10 KB dbuf [n][d2(16)+pad]
  __shared__ unsigned phi_pr[KK][4], phi_pi[KK][4];

  int t = threadIdx.x;
  int lane = t & 63;
  int w = t >> 6;                // wave 0..3
  int l15 = lane & 15;
  int l4 = lane >> 4;            // 0..3
  int rt = blockIdx.x;           // 0..256
  int r0 = rt << 2;
  int h0 = blockIdx.y << 7;      // 0 or 128
  int hrow = h0 + w * 32 + l15;  // A row for fm=0

  if (t < 96) {
    int k = t >> 2, rl = t & 3;
    int rc = min(r0 + rl, RR - 1);
    float pr = Phi_re[k * RR + rc], pi = Phi_im[k * RR + rc];
    phi_pr[k][rl] = __builtin_bit_cast(unsigned, __floats2half2_rn(pr, pr));
    phi_pi[k][rl] = __builtin_bit_cast(unsigned, __floats2half2_rn(pi, pi));
  }

  f32x4 acc[2][4];
  #pragma unroll
  for (int fm = 0; fm < 2; ++fm)
    #pragma unroll
    for (int fn = 0; fn < 4; ++fn) acc[fm][fn] = (f32x4){0.f, 0.f, 0.f, 0.f};

  for (int win = 0; win < 4; ++win) {
    __syncthreads();               // protect xs from prior window's builds
    // stage Xf window: 64 d (32 pairs) x 4 r x 8 b
    #pragma unroll
    for (int e = 0; e < 4; ++e) {
      int idx = t + 256 * e;
      int d2 = idx >> 5, rl = (idx >> 3) & 3, b = idx & 7;
      int d = win * 64 + 2 * d2;
      int rc = min(r0 + rl, RR - 1);
      unsigned u0 = Xf2[(size_t)(b * DD + d) * RR + rc];
      unsigned u1 = Xf2[(size_t)(b * DD + d + 1) * RR + rc];
      xs_r[d2][rl][b] = (u0 & 0xffffu) | (u1 << 16);
      xs_i[d2][rl][b] = (u0 >> 16) | (u1 & 0xffff0000u);
    }
    __syncthreads();
    SPEC_BUILD(0, 0, 0);           // chunk 0 of this window
    __syncthreads();
    for (int cc = 0; cc < 48; ++cc) {
      int k = cc >> 1, ds = cc & 1;
      int kdbase = k * 256 + win * 64 + ds * 32;
      // A fragments (global, f16, contiguous 8 along kd)
      f16x8 af0 = *reinterpret_cast<const f16x8*>(
          A2 + (size_t)hrow * 6144 + kdbase + l4 * 8);
      f16x8 af1 = *reinterpret_cast<const f16x8*>(
          A2 + (size_t)(hrow + 16) * 6144 + kdbase + l4 * 8);
      if (cc < 47) {
        int k2 = (cc + 1) >> 1, ds2 = (cc + 1) & 1, bf2 = (cc + 1) & 1;
        SPEC_BUILD(k2, ds2, bf2);
      }
      int buf = cc & 1;
      #pragma unroll
      for (int fn = 0; fn < 4; ++fn) {
        f16x8 bf = *reinterpret_cast<const f16x8*>(&Bl[buf][fn * 16 + l15][l4 * 4]);
        acc[0][fn] = __builtin_amdgcn_mfma_f32_16x16x32_f16(af0, bf, acc[0][fn], 0, 0, 0);
        acc[1][fn] = __builtin_amdgcn_mfma_f32_16x16x32_f16(af1, bf, acc[1][fn], 0, 0, 0);
      }
      __syncthreads();
    }
  }

  // epilogue: C[h][n], col = l15, rows = l4*4 + i (+16*fm)
  float* Sff = reinterpret_cast<float*>(Sf);
  int b = l15 >> 1, ri = l15 & 1;
  #pragma unroll
  for (int fm = 0; fm < 2; ++fm)
    #pragma unroll
    for (int fn = 0; fn < 4; ++fn) {
      int r = min(r0 + fn, RR - 1);
      #pragma unroll
      for (int i = 0; i < 4; ++i) {
        int h = h0 + w * 32 + fm * 16 + l4 * 4 + i;
        Sff[((((size_t)(b * DD + h)) * RR + r) << 1) + ri] = acc[fm][fn][i];
      }
    }
}

// ---------------- fused MLP + residual, f32 output ----------------
__global__ void mlp_kernel(const float* __restrict__ S, const float* __restrict__ x,
                           const float* __restrict__ W1T, const float* __restrict__ b1,
                           const float* __restrict__ W2T, const float* __restrict__ b2,
                           float* __restrict__ out) {
  __shared__ float s_s[DD][32];
  __shared__ float h_s[128][36];
  int b = blockIdx.y;
  int l0 = blockIdx.x << 5;
  int t = threadIdx.x;
  {
    const float* Sp = S + ((size_t)(b * DD + t)) * LL + l0;
    float4* drow = reinterpret_cast<float4*>(&s_s[t][0]);
    const float4* srow = reinterpret_cast<const float4*>(Sp);
    #pragma unroll
    for (int j = 0; j < 8; ++j) drow[j] = srow[j];
  }
  int h_loc = t >> 1;
  int lhalf = t & 1;
  float acc[32];
  #pragma unroll
  for (int i = 0; i < 32; ++i) acc[i] = 0.f;

  for (int hcBase = 0; hcBase < HH; hcBase += 128) {
    __syncthreads();
    int h = hcBase + h_loc;
    float a[16];
    float bias = b1[h];
    #pragma unroll
    for (int i = 0; i < 16; ++i) a[i] = bias;
    for (int c = 0; c < DD; ++c) {
      float w = W1T[(size_t)c * HH + h];
      const float4* sv4 = reinterpret_cast<const float4*>(&s_s[c][lhalf * 16]);
      #pragma unroll
      for (int j = 0; j < 4; ++j) {
        float4 sv = sv4[j];
        a[j * 4 + 0] += w * sv.x; a[j * 4 + 1] += w * sv.y;
        a[j * 4 + 2] += w * sv.z; a[j * 4 + 3] += w * sv.w;
      }
    }
    #pragma unroll
    for (int i = 0; i < 16; ++i) {
      float v = a[i];
      h_s[h_loc][lhalf * 16 + i] = 0.5f * v * (1.f + erff(v * 0.70710678118654752f));
    }
    __syncthreads();
    for (int hh = 0; hh < 128; ++hh) {
      float w = W2T[(size_t)(hcBase + hh) * DD + t];
      const float4* hv4 = reinterpret_cast<const float4*>(&h_s[hh][0]);
      #pragma unroll
      for (int j = 0; j < 8; ++j) {
        float4 hv = hv4[j];
        acc[j * 4 + 0] += w * hv.x; acc[j * 4 + 1] += w * hv.y;
        acc[j * 4 + 2] += w * hv.z; acc[j * 4 + 3] += w * hv.w;
      }
    }
  }
  const float* xp = x + ((size_t)(b * DD + t)) * LL + l0;
  float* op = out + ((size_t)(b * DD + t)) * LL + l0;
  float bb2 = b2[t];
  #pragma unroll
  for (int j = 0; j < 8; ++j) {
    float4 xv = reinterpret_cast<const float4*>(xp)[j];
    float4 o;
    o.x = xv.x + bb2 + acc[j * 4 + 0];
    o.y = xv.y + bb2 + acc[j * 4 + 1];
    o.z = xv.z + bb2 + acc[j * 4 + 2];
    o.w = xv.w + bb2 + acc[j * 4 + 3];
    reinterpret_cast<float4*>(op)[j] = o;
  }
}

extern "C" void kernel_launch(void* const* d_in, const int* in_sizes, int n_in,
                              void* d_out, int out_size, void* d_ws, size_t ws_size,
                              hipStream_t stream) {
  const float* x      = (const float*)d_in[0];
  const float* Phi_re = (const float*)d_in[1];
  const float* Phi_im = (const float*)d_in[2];
  const float* Theta  = (const float*)d_in[3];
  const float* gamma  = (const float*)d_in[4];
  const float* beta   = (const float*)d_in[5];
  const float* W1     = (const float*)d_in[6];
  const float* b1     = (const float*)d_in[7];
  const float* W2     = (const float*)d_in[8];
  const float* b2     = (const float*)d_in[9];

  float* ws = (float*)d_ws;
  float*    z   = ws;                            // 4,194,304 f (reused for S)
  unsigned* Xf2 = (unsigned*)(ws + 4194304);     // 2,099,200 u32 (f16 pairs)
  float2*   Sf  = (float2*)(ws + 8392704);       // 2,099,200 float2
  unsigned* A2u = (unsigned*)(ws + 12591104);    // 786,432 u32 (f16 Theta)
  float*    W1T = ws + 14163968;                 // 131,072
  float*    W2T = ws + 14295040;                 // 131,072

  ln_kernel<<<dim3(BB * (LL / 64)), 256, 0, stream>>>(x, gamma, beta, z);
  theta_prep<<<dim3(KK * 256), 128, 0, stream>>>(Theta, A2u);
  transpose_kernel<<<dim3(8, 16, 1), dim3(32, 8), 0, stream>>>(W1, W1T, 512, 256);
  transpose_kernel<<<dim3(16, 8, 1), dim3(32, 8), 0, stream>>>(W2, W2T, 256, 512);
  rfft_kernel<<<dim3(BB * DD), 256, 0, stream>>>(z, Xf2);
  spectral_mfma<<<dim3(257, 2), 256, 0, stream>>>(
      Xf2, (const unsigned short*)A2u, Phi_re, Phi_im, Sf);
  irfft_kernel<<<dim3(BB * DD), 256, 0, stream>>>(Sf, z);      // S -> z
  mlp_kernel<<<dim3(LL / 32, BB), 256, 0, stream>>>(z, x, W1T, b1, W2T, b2,
                                                    (float*)d_out);
}

// Round 12
// 414.162 us; speedup vs baseline: 1.9946x; 1.1402x over previous
//
#include <hip/hip_runtime.h>
#include <hip/hip_bf16.h>
#include <hip/hip_fp16.h>
#include <math.h>

#define BB 8
#define DD 256
#define LL 2048
#define KK 24
#define RR 1025
#define HH 512

typedef __attribute__((ext_vector_type(8))) _Float16 f16x8;
typedef __attribute__((ext_vector_type(4))) float f32x4;

// ---------------- LayerNorm over channel dim D, per (b,l) ----------------
__global__ void ln_kernel(const float* __restrict__ x, const float* __restrict__ gamma,
                          const float* __restrict__ beta, float* __restrict__ z) {
  __shared__ float red[2][4][64];
  __shared__ float mu_s[64], rs_s[64];
  int blk = blockIdx.x;
  int b = blk >> 5;
  int l0 = (blk & 31) << 6;
  int t = threadIdx.x;
  int ll = t & 63;
  int part = t >> 6;
  int l = l0 + ll;
  const float* xb = x + ((size_t)b * DD) * LL + l;
  float xv[64];
  float s = 0.f, ss = 0.f;
  #pragma unroll
  for (int i = 0; i < 64; ++i) {
    float v = xb[(size_t)(part * 64 + i) * LL];
    xv[i] = v; s += v; ss += v * v;
  }
  red[0][part][ll] = s; red[1][part][ll] = ss;
  __syncthreads();
  if (part == 0) {
    float S = red[0][0][ll] + red[0][1][ll] + red[0][2][ll] + red[0][3][ll];
    float Q = red[1][0][ll] + red[1][1][ll] + red[1][2][ll] + red[1][3][ll];
    float mu = S * (1.f / 256.f);
    float var = Q * (1.f / 256.f) - mu * mu;
    mu_s[ll] = mu; rs_s[ll] = rsqrtf(var + 1e-5f);
  }
  __syncthreads();
  float mu = mu_s[ll], rs = rs_s[ll];
  float* zb = z + ((size_t)b * DD) * LL + l;
  #pragma unroll
  for (int i = 0; i < 64; ++i) {
    int d = part * 64 + i;
    zb[(size_t)d * LL] = (xv[i] - mu) * rs * gamma[d] + beta[d];
  }
}

// ---------------- generic 32x32 tiled transpose ----------------
__global__ void transpose_kernel(const float* __restrict__ src, float* __restrict__ dst,
                                 int rows, int cols) {
  __shared__ float tile[32][33];
  int mat = blockIdx.z;
  const float* s = src + (size_t)mat * rows * cols;
  float* d = dst + (size_t)mat * rows * cols;
  int c0 = blockIdx.x * 32, r0 = blockIdx.y * 32;
  for (int i = threadIdx.y; i < 32; i += 8)
    tile[i][threadIdx.x] = s[(size_t)(r0 + i) * cols + c0 + threadIdx.x];
  __syncthreads();
  for (int i = threadIdx.y; i < 32; i += 8)
    d[(size_t)(c0 + i) * rows + r0 + threadIdx.x] = tile[threadIdx.x][i];
}

// ---------------- Theta -> f16 A2[h][k*256+d] ----------------
__global__ void theta_prep(const float* __restrict__ Theta, unsigned* __restrict__ A2u) {
  int bi = blockIdx.x;
  int k = bi >> 8, h = bi & 255;
  int t = threadIdx.x;   // 0..127, d = 2t
  float2 v = *reinterpret_cast<const float2*>(Theta + (size_t)k * 65536 + h * 256 + 2 * t);
  A2u[(size_t)h * 3072 + k * 128 + t] =
      __builtin_bit_cast(unsigned, __floats2half2_rn(v.x, v.y));
}

// ---------------- Stockham radix-2 FFT, n=2048, in LDS ----------------
__device__ __forceinline__ float2* fft2048(float2* bufA, float2* bufB,
                                           const float2* __restrict__ tw, int t) {
  float2* src = bufA; float2* dst = bufB;
  for (int stage = 0; stage < 11; ++stage) {
    int s = 1 << stage;
    #pragma unroll
    for (int j = 0; j < 4; ++j) {
      int idx = t + 256 * j;
      int q = idx & (s - 1);
      int p = idx >> stage;
      float2 a = src[idx];
      float2 b = src[idx + 1024];
      float sr = a.x + b.x, si = a.y + b.y;
      float dr = a.x - b.x, di = a.y - b.y;
      float2 w = tw[p << stage];
      dst[q + 2 * s * p] = make_float2(sr, si);
      dst[q + 2 * s * p + s] = make_float2(dr * w.x - di * w.y, dr * w.y + di * w.x);
    }
    __syncthreads();
    float2* tmp = src; src = dst; dst = tmp;
  }
  return src;
}

__device__ __forceinline__ void build_tw(float2* tw, int t) {
  #pragma unroll
  for (int j = 0; j < 4; ++j) {
    int i = t + 256 * j;
    float xfrac = (float)i * (1.f / 1024.f);
    tw[i] = make_float2(cospif(xfrac), -sinpif(xfrac));
  }
}

// rfft -> packed f16 (re,im) per bin
__global__ void rfft_kernel(const float* __restrict__ z, unsigned* __restrict__ Xf2) {
  __shared__ float2 bufA[2048];
  __shared__ float2 bufB[2048];
  __shared__ float2 tw[1024];
  int row = blockIdx.x;
  int t = threadIdx.x;
  build_tw(tw, t);
  const float* zr = z + (size_t)row * LL;
  #pragma unroll
  for (int j = 0; j < 8; ++j) {
    int i = t + 256 * j;
    bufA[i] = make_float2(zr[i], 0.f);
  }
  __syncthreads();
  float2* res = fft2048(bufA, bufB, tw, t);
  #pragma unroll
  for (int j = 0; j < 5; ++j) {
    int r = t + 256 * j;
    if (r <= 1024) {
      float2 v = res[r];
      Xf2[(size_t)row * RR + r] = __builtin_bit_cast(unsigned, __floats2half2_rn(v.x, v.y));
    }
  }
}

// irfft(F, n=2048) = real( fft( conj(F_full) ) ) / 2048
__global__ void irfft_kernel(const float2* __restrict__ Sf, float* __restrict__ S) {
  __shared__ float2 bufA[2048];
  __shared__ float2 bufB[2048];
  __shared__ float2 tw[1024];
  int row = blockIdx.x;
  int t = threadIdx.x;
  build_tw(tw, t);
  const float2* fr = Sf + (size_t)row * RR;
  #pragma unroll
  for (int j = 0; j < 8; ++j) {
    int i = t + 256 * j;
    float2 v;
    if (i <= 1024) { v = fr[i]; v.y = -v.y; }
    else           { v = fr[2048 - i]; }
    bufA[i] = v;
  }
  __syncthreads();
  float2* res = fft2048(bufA, bufB, tw, t);
  const float scale = 1.f / 2048.f;
  float* sr = S + (size_t)row * LL;
  #pragma unroll
  for (int j = 0; j < 8; ++j) {
    int i = t + 256 * j;
    sr[i] = res[i].x * scale;
  }
}

// ---------------- spectral mixing as f16 MFMA GEMM ----------------
// Sf[h,(b,r,ri)] = sum_{kd} A2[h][kd] * B[kd][(r_l,b,ri)]
// xs stride = 34 dwords: bank = (2*d2 + rl*8 + b) % 32 -> exact 2-way (free).
#define SPEC_BUILD(kk, dss, bbuf)                                              \
  {                                                                            \
    int d2l_ = t & 15;                                                         \
    int pp_ = t >> 4;                                                          \
    _Pragma("unroll")                                                          \
    for (int j_ = 0; j_ < 2; ++j_) {                                           \
      int p_ = pp_ + 16 * j_;                                                  \
      int rl_ = p_ >> 3, bb_ = p_ & 7;                                         \
      unsigned xr_ = xs_r[(dss) * 16 + d2l_][rl_ * 8 + bb_];                   \
      unsigned xi_ = xs_i[(dss) * 16 + d2l_][rl_ * 8 + bb_];                   \
      __half2 pr_ = __builtin_bit_cast(__half2, phi_pr[kk][rl_]);              \
      __half2 pi_ = __builtin_bit_cast(__half2, phi_pi[kk][rl_]);              \
      __half2 xrh_ = __builtin_bit_cast(__half2, xr_);                         \
      __half2 xih_ = __builtin_bit_cast(__half2, xi_);                         \
      __half2 re_ = __hfma2(xrh_, pr_, __hmul2(xih_, pi_));                    \
      __half2 im_ = __hfma2(xih_, pr_, __hneg2(__hmul2(xrh_, pi_)));           \
      Bl[bbuf][2 * p_][d2l_] = __builtin_bit_cast(unsigned, re_);              \
      Bl[bbuf][2 * p_ + 1][d2l_] = __builtin_bit_cast(unsigned, im_);          \
    }                                                                          \
  }

__global__ void __launch_bounds__(256)
spectral_mfma(const unsigned* __restrict__ Xf2,        // [(b*256+d)][1025] half2
              const unsigned short* __restrict__ A2,   // [h][6144] f16
              const float* __restrict__ Phi_re,
              const float* __restrict__ Phi_im,
              float2* __restrict__ Sf) {
  __shared__ unsigned xs_r[32][34];              // 4.25 KB (d2, rl*8+b), 2-way banks
  __shared__ unsigned xs_i[32][34];              // 4.25 KB
  __shared__ alignas(16) unsigned Bl[2][64][20]; // 10 KB dbuf [n][d2(16)+pad]
  __shared__ unsigned phi_pr[KK][4], phi_pi[KK][4];

  int t = threadIdx.x;
  int lane = t & 63;
  int w = t >> 6;                // wave 0..3
  int l15 = lane & 15;
  int l4 = lane >> 4;            // 0..3
  int rt = blockIdx.x;           // 0..256
  int r0 = rt << 2;
  int h0 = blockIdx.y << 7;      // 0 or 128
  int hrow = h0 + w * 32 + l15;  // A row for fm=0

  if (t < 96) {
    int k = t >> 2, rl = t & 3;
    int rc = min(r0 + rl, RR - 1);
    float pr = Phi_re[k * RR + rc], pi = Phi_im[k * RR + rc];
    phi_pr[k][rl] = __builtin_bit_cast(unsigned, __floats2half2_rn(pr, pr));
    phi_pi[k][rl] = __builtin_bit_cast(unsigned, __floats2half2_rn(pi, pi));
  }

  f32x4 acc[2][4];
  #pragma unroll
  for (int fm = 0; fm < 2; ++fm)
    #pragma unroll
    for (int fn = 0; fn < 4; ++fn) acc[fm][fn] = (f32x4){0.f, 0.f, 0.f, 0.f};

  for (int win = 0; win < 4; ++win) {
    __syncthreads();               // protect xs from prior window's builds
    // stage Xf window: 64 d (32 pairs) x 4 r x 8 b
    #pragma unroll
    for (int e = 0; e < 4; ++e) {
      int idx = t + 256 * e;
      int d2 = idx >> 5, rl = (idx >> 3) & 3, b = idx & 7;
      int d = win * 64 + 2 * d2;
      int rc = min(r0 + rl, RR - 1);
      unsigned u0 = Xf2[(size_t)(b * DD + d) * RR + rc];
      unsigned u1 = Xf2[(size_t)(b * DD + d + 1) * RR + rc];
      xs_r[d2][rl * 8 + b] = (u0 & 0xffffu) | (u1 << 16);
      xs_i[d2][rl * 8 + b] = (u0 >> 16) | (u1 & 0xffff0000u);
    }
    __syncthreads();
    SPEC_BUILD(0, 0, 0);           // chunk 0 of this window
    __syncthreads();
    for (int cc = 0; cc < 48; ++cc) {
      int k = cc >> 1, ds = cc & 1;
      int kdbase = k * 256 + win * 64 + ds * 32;
      // A fragments (global, f16, contiguous 8 along kd)
      f16x8 af0 = *reinterpret_cast<const f16x8*>(
          A2 + (size_t)hrow * 6144 + kdbase + l4 * 8);
      f16x8 af1 = *reinterpret_cast<const f16x8*>(
          A2 + (size_t)(hrow + 16) * 6144 + kdbase + l4 * 8);
      if (cc < 47) {
        int k2 = (cc + 1) >> 1, ds2 = (cc + 1) & 1, bf2 = (cc + 1) & 1;
        SPEC_BUILD(k2, ds2, bf2);
      }
      int buf = cc & 1;
      #pragma unroll
      for (int fn = 0; fn < 4; ++fn) {
        f16x8 bf = *reinterpret_cast<const f16x8*>(&Bl[buf][fn * 16 + l15][l4 * 4]);
        acc[0][fn] = __builtin_amdgcn_mfma_f32_16x16x32_f16(af0, bf, acc[0][fn], 0, 0, 0);
        acc[1][fn] = __builtin_amdgcn_mfma_f32_16x16x32_f16(af1, bf, acc[1][fn], 0, 0, 0);
      }
      __syncthreads();
    }
  }

  // epilogue: C[h][n], col = l15, rows = l4*4 + i (+16*fm)
  float* Sff = reinterpret_cast<float*>(Sf);
  int b = l15 >> 1, ri = l15 & 1;
  #pragma unroll
  for (int fm = 0; fm < 2; ++fm)
    #pragma unroll
    for (int fn = 0; fn < 4; ++fn) {
      int r = min(r0 + fn, RR - 1);
      #pragma unroll
      for (int i = 0; i < 4; ++i) {
        int h = h0 + w * 32 + fm * 16 + l4 * 4 + i;
        Sff[((((size_t)(b * DD + h)) * RR + r) << 1) + ri] = acc[fm][fn][i];
      }
    }
}

// ---------------- fused MLP + residual, f32 output ----------------
__global__ void mlp_kernel(const float* __restrict__ S, const float* __restrict__ x,
                           const float* __restrict__ W1T, const float* __restrict__ b1,
                           const float* __restrict__ W2T, const float* __restrict__ b2,
                           float* __restrict__ out) {
  __shared__ float s_s[DD][32];
  __shared__ float h_s[128][36];
  int b = blockIdx.y;
  int l0 = blockIdx.x << 5;
  int t = threadIdx.x;
  {
    const float* Sp = S + ((size_t)(b * DD + t)) * LL + l0;
    float4* drow = reinterpret_cast<float4*>(&s_s[t][0]);
    const float4* srow = reinterpret_cast<const float4*>(Sp);
    #pragma unroll
    for (int j = 0; j < 8; ++j) drow[j] = srow[j];
  }
  int h_loc = t >> 1;
  int lhalf = t & 1;
  float acc[32];
  #pragma unroll
  for (int i = 0; i < 32; ++i) acc[i] = 0.f;

  for (int hcBase = 0; hcBase < HH; hcBase += 128) {
    __syncthreads();
    int h = hcBase + h_loc;
    float a[16];
    float bias = b1[h];
    #pragma unroll
    for (int i = 0; i < 16; ++i) a[i] = bias;
    for (int c = 0; c < DD; ++c) {
      float w = W1T[(size_t)c * HH + h];
      const float4* sv4 = reinterpret_cast<const float4*>(&s_s[c][lhalf * 16]);
      #pragma unroll
      for (int j = 0; j < 4; ++j) {
        float4 sv = sv4[j];
        a[j * 4 + 0] += w * sv.x; a[j * 4 + 1] += w * sv.y;
        a[j * 4 + 2] += w * sv.z; a[j * 4 + 3] += w * sv.w;
      }
    }
    #pragma unroll
    for (int i = 0; i < 16; ++i) {
      float v = a[i];
      h_s[h_loc][lhalf * 16 + i] = 0.5f * v * (1.f + erff(v * 0.70710678118654752f));
    }
    __syncthreads();
    for (int hh = 0; hh < 128; ++hh) {
      float w = W2T[(size_t)(hcBase + hh) * DD + t];
      const float4* hv4 = reinterpret_cast<const float4*>(&h_s[hh][0]);
      #pragma unroll
      for (int j = 0; j < 8; ++j) {
        float4 hv = hv4[j];
        acc[j * 4 + 0] += w * hv.x; acc[j * 4 + 1] += w * hv.y;
        acc[j * 4 + 2] += w * hv.z; acc[j * 4 + 3] += w * hv.w;
      }
    }
  }
  const float* xp = x + ((size_t)(b * DD + t)) * LL + l0;
  float* op = out + ((size_t)(b * DD + t)) * LL + l0;
  float bb2 = b2[t];
  #pragma unroll
  for (int j = 0; j < 8; ++j) {
    float4 xv = reinterpret_cast<const float4*>(xp)[j];
    float4 o;
    o.x = xv.x + bb2 + acc[j * 4 + 0];
    o.y = xv.y + bb2 + acc[j * 4 + 1];
    o.z = xv.z + bb2 + acc[j * 4 + 2];
    o.w = xv.w + bb2 + acc[j * 4 + 3];
    reinterpret_cast<float4*>(op)[j] = o;
  }
}

extern "C" void kernel_launch(void* const* d_in, const int* in_sizes, int n_in,
                              void* d_out, int out_size, void* d_ws, size_t ws_size,
                              hipStream_t stream) {
  const float* x      = (const float*)d_in[0];
  const float* Phi_re = (const float*)d_in[1];
  const float* Phi_im = (const float*)d_in[2];
  const float* Theta  = (const float*)d_in[3];
  const float* gamma  = (const float*)d_in[4];
  const float* beta   = (const float*)d_in[5];
  const float* W1     = (const float*)d_in[6];
  const float* b1     = (const float*)d_in[7];
  const float* W2     = (const float*)d_in[8];
  const float* b2     = (const float*)d_in[9];

  float* ws = (float*)d_ws;
  float*    z   = ws;                            // 4,194,304 f (reused for S)
  unsigned* Xf2 = (unsigned*)(ws + 4194304);     // 2,099,200 u32 (f16 pairs)
  float2*   Sf  = (float2*)(ws + 8392704);       // 2,099,200 float2
  unsigned* A2u = (unsigned*)(ws + 12591104);    // 786,432 u32 (f16 Theta)
  float*    W1T = ws + 14163968;                 // 131,072
  float*    W2T = ws + 14295040;                 // 131,072

  ln_kernel<<<dim3(BB * (LL / 64)), 256, 0, stream>>>(x, gamma, beta, z);
  theta_prep<<<dim3(KK * 256), 128, 0, stream>>>(Theta, A2u);
  transpose_kernel<<<dim3(8, 16, 1), dim3(32, 8), 0, stream>>>(W1, W1T, 512, 256);
  transpose_kernel<<<dim3(16, 8, 1), dim3(32, 8), 0, stream>>>(W2, W2T, 256, 512);
  rfft_kernel<<<dim3(BB * DD), 256, 0, stream>>>(z, Xf2);
  spectral_mfma<<<dim3(257, 2), 256, 0, stream>>>(
      Xf2, (const unsigned short*)A2u, Phi_re, Phi_im, Sf);
  irfft_kernel<<<dim3(BB * DD), 256, 0, stream>>>(Sf, z);      // S -> z
  mlp_kernel<<<dim3(LL / 32, BB), 256, 0, stream>>>(z, x, W1T, b1, W2T, b2,
                                                    (float*)d_out);
}

// Round 13
// 264.994 us; speedup vs baseline: 3.1173x; 1.5629x over previous
//
#include <hip/hip_runtime.h>
#include <hip/hip_bf16.h>
#include <hip/hip_fp16.h>
#include <math.h>

#define BB 8
#define DD 256
#define LL 2048
#define KK 24
#define RR 1025
#define HH 512

typedef __attribute__((ext_vector_type(8))) _Float16 f16x8;
typedef __attribute__((ext_vector_type(4))) float f32x4;

__device__ __forceinline__ unsigned short f2h(float f) {
  return __builtin_bit_cast(unsigned short, __float2half_rn(f));
}

// ---------------- LayerNorm over channel dim D, per (b,l) ----------------
__global__ void ln_kernel(const float* __restrict__ x, const float* __restrict__ gamma,
                          const float* __restrict__ beta, float* __restrict__ z) {
  __shared__ float red[2][4][64];
  __shared__ float mu_s[64], rs_s[64];
  int blk = blockIdx.x;
  int b = blk >> 5;
  int l0 = (blk & 31) << 6;
  int t = threadIdx.x;
  int ll = t & 63;
  int part = t >> 6;
  int l = l0 + ll;
  const float* xb = x + ((size_t)b * DD) * LL + l;
  float xv[64];
  float s = 0.f, ss = 0.f;
  #pragma unroll
  for (int i = 0; i < 64; ++i) {
    float v = xb[(size_t)(part * 64 + i) * LL];
    xv[i] = v; s += v; ss += v * v;
  }
  red[0][part][ll] = s; red[1][part][ll] = ss;
  __syncthreads();
  if (part == 0) {
    float S = red[0][0][ll] + red[0][1][ll] + red[0][2][ll] + red[0][3][ll];
    float Q = red[1][0][ll] + red[1][1][ll] + red[1][2][ll] + red[1][3][ll];
    float mu = S * (1.f / 256.f);
    float var = Q * (1.f / 256.f) - mu * mu;
    mu_s[ll] = mu; rs_s[ll] = rsqrtf(var + 1e-5f);
  }
  __syncthreads();
  float mu = mu_s[ll], rs = rs_s[ll];
  float* zb = z + ((size_t)b * DD) * LL + l;
  #pragma unroll
  for (int i = 0; i < 64; ++i) {
    int d = part * 64 + i;
    zb[(size_t)d * LL] = (xv[i] - mu) * rs * gamma[d] + beta[d];
  }
}

// ---------------- Theta -> f16 A2[h][k*256+d] ----------------
__global__ void theta_prep(const float* __restrict__ Theta, unsigned* __restrict__ A2u) {
  int bi = blockIdx.x;
  int k = bi >> 8, h = bi & 255;
  int t = threadIdx.x;   // 0..127, d = 2t
  float2 v = *reinterpret_cast<const float2*>(Theta + (size_t)k * 65536 + h * 256 + 2 * t);
  A2u[(size_t)h * 3072 + k * 128 + t] =
      __builtin_bit_cast(unsigned, __floats2half2_rn(v.x, v.y));
}

// ---------------- W1/W2 -> f16 (same layouts) ----------------
__global__ void w_prep(const float* __restrict__ W1, const float* __restrict__ W2,
                       unsigned* __restrict__ W1h, unsigned* __restrict__ W2h) {
  int i = blockIdx.x * 256 + threadIdx.x;        // 0..65535, pairs
  float2 a = reinterpret_cast<const float2*>(W1)[i];
  W1h[i] = __builtin_bit_cast(unsigned, __floats2half2_rn(a.x, a.y));
  float2 b = reinterpret_cast<const float2*>(W2)[i];
  W2h[i] = __builtin_bit_cast(unsigned, __floats2half2_rn(b.x, b.y));
}

// ---------------- Stockham radix-2 FFT, n=2048, in LDS ----------------
__device__ __forceinline__ float2* fft2048(float2* bufA, float2* bufB,
                                           const float2* __restrict__ tw, int t) {
  float2* src = bufA; float2* dst = bufB;
  for (int stage = 0; stage < 11; ++stage) {
    int s = 1 << stage;
    #pragma unroll
    for (int j = 0; j < 4; ++j) {
      int idx = t + 256 * j;
      int q = idx & (s - 1);
      int p = idx >> stage;
      float2 a = src[idx];
      float2 b = src[idx + 1024];
      float sr = a.x + b.x, si = a.y + b.y;
      float dr = a.x - b.x, di = a.y - b.y;
      float2 w = tw[p << stage];
      dst[q + 2 * s * p] = make_float2(sr, si);
      dst[q + 2 * s * p + s] = make_float2(dr * w.x - di * w.y, dr * w.y + di * w.x);
    }
    __syncthreads();
    float2* tmp = src; src = dst; dst = tmp;
  }
  return src;
}

__device__ __forceinline__ void build_tw(float2* tw, int t) {
  #pragma unroll
  for (int j = 0; j < 4; ++j) {
    int i = t + 256 * j;
    float xfrac = (float)i * (1.f / 1024.f);
    tw[i] = make_float2(cospif(xfrac), -sinpif(xfrac));
  }
}

// rfft -> packed f16 (re,im) per bin
__global__ void rfft_kernel(const float* __restrict__ z, unsigned* __restrict__ Xf2) {
  __shared__ float2 bufA[2048];
  __shared__ float2 bufB[2048];
  __shared__ float2 tw[1024];
  int row = blockIdx.x;
  int t = threadIdx.x;
  build_tw(tw, t);
  const float* zr = z + (size_t)row * LL;
  #pragma unroll
  for (int j = 0; j < 8; ++j) {
    int i = t + 256 * j;
    bufA[i] = make_float2(zr[i], 0.f);
  }
  __syncthreads();
  float2* res = fft2048(bufA, bufB, tw, t);
  #pragma unroll
  for (int j = 0; j < 5; ++j) {
    int r = t + 256 * j;
    if (r <= 1024) {
      float2 v = res[r];
      Xf2[(size_t)row * RR + r] = __builtin_bit_cast(unsigned, __floats2half2_rn(v.x, v.y));
    }
  }
}

// irfft(F, n=2048) = real( fft( conj(F_full) ) ) / 2048
__global__ void irfft_kernel(const float2* __restrict__ Sf, float* __restrict__ S) {
  __shared__ float2 bufA[2048];
  __shared__ float2 bufB[2048];
  __shared__ float2 tw[1024];
  int row = blockIdx.x;
  int t = threadIdx.x;
  build_tw(tw, t);
  const float2* fr = Sf + (size_t)row * RR;
  #pragma unroll
  for (int j = 0; j < 8; ++j) {
    int i = t + 256 * j;
    float2 v;
    if (i <= 1024) { v = fr[i]; v.y = -v.y; }
    else           { v = fr[2048 - i]; }
    bufA[i] = v;
  }
  __syncthreads();
  float2* res = fft2048(bufA, bufB, tw, t);
  const float scale = 1.f / 2048.f;
  float* sr = S + (size_t)row * LL;
  #pragma unroll
  for (int j = 0; j < 8; ++j) {
    int i = t + 256 * j;
    sr[i] = res[i].x * scale;
  }
}

// ---------------- spectral mixing as f16 MFMA GEMM ----------------
#define SPEC_BUILD(kk, dss, bbuf)                                              \
  {                                                                            \
    int d2l_ = t & 15;                                                         \
    int pp_ = t >> 4;                                                          \
    _Pragma("unroll")                                                          \
    for (int j_ = 0; j_ < 2; ++j_) {                                           \
      int p_ = pp_ + 16 * j_;                                                  \
      int rl_ = p_ >> 3, bb_ = p_ & 7;                                         \
      unsigned xr_ = xs_r[(dss) * 16 + d2l_][rl_ * 8 + bb_];                   \
      unsigned xi_ = xs_i[(dss) * 16 + d2l_][rl_ * 8 + bb_];                   \
      __half2 pr_ = __builtin_bit_cast(__half2, phi_pr[kk][rl_]);              \
      __half2 pi_ = __builtin_bit_cast(__half2, phi_pi[kk][rl_]);              \
      __half2 xrh_ = __builtin_bit_cast(__half2, xr_);                         \
      __half2 xih_ = __builtin_bit_cast(__half2, xi_);                         \
      __half2 re_ = __hfma2(xrh_, pr_, __hmul2(xih_, pi_));                    \
      __half2 im_ = __hfma2(xih_, pr_, __hneg2(__hmul2(xrh_, pi_)));           \
      Bl[bbuf][2 * p_][d2l_] = __builtin_bit_cast(unsigned, re_);              \
      Bl[bbuf][2 * p_ + 1][d2l_] = __builtin_bit_cast(unsigned, im_);          \
    }                                                                          \
  }

__global__ void __launch_bounds__(256)
spectral_mfma(const unsigned* __restrict__ Xf2,        // [(b*256+d)][1025] half2
              const unsigned short* __restrict__ A2,   // [h][6144] f16
              const float* __restrict__ Phi_re,
              const float* __restrict__ Phi_im,
              float2* __restrict__ Sf) {
  __shared__ unsigned xs_r[32][34];
  __shared__ unsigned xs_i[32][34];
  __shared__ alignas(16) unsigned Bl[2][64][20];
  __shared__ unsigned phi_pr[KK][4], phi_pi[KK][4];

  int t = threadIdx.x;
  int lane = t & 63;
  int w = t >> 6;
  int l15 = lane & 15;
  int l4 = lane >> 4;
  int rt = blockIdx.x;
  int r0 = rt << 2;
  int h0 = blockIdx.y << 7;
  int hrow = h0 + w * 32 + l15;

  if (t < 96) {
    int k = t >> 2, rl = t & 3;
    int rc = min(r0 + rl, RR - 1);
    float pr = Phi_re[k * RR + rc], pi = Phi_im[k * RR + rc];
    phi_pr[k][rl] = __builtin_bit_cast(unsigned, __floats2half2_rn(pr, pr));
    phi_pi[k][rl] = __builtin_bit_cast(unsigned, __floats2half2_rn(pi, pi));
  }

  f32x4 acc[2][4];
  #pragma unroll
  for (int fm = 0; fm < 2; ++fm)
    #pragma unroll
    for (int fn = 0; fn < 4; ++fn) acc[fm][fn] = (f32x4){0.f, 0.f, 0.f, 0.f};

  for (int win = 0; win < 4; ++win) {
    __syncthreads();
    #pragma unroll
    for (int e = 0; e < 4; ++e) {
      int idx = t + 256 * e;
      int d2 = idx >> 5, rl = (idx >> 3) & 3, b = idx & 7;
      int d = win * 64 + 2 * d2;
      int rc = min(r0 + rl, RR - 1);
      unsigned u0 = Xf2[(size_t)(b * DD + d) * RR + rc];
      unsigned u1 = Xf2[(size_t)(b * DD + d + 1) * RR + rc];
      xs_r[d2][rl * 8 + b] = (u0 & 0xffffu) | (u1 << 16);
      xs_i[d2][rl * 8 + b] = (u0 >> 16) | (u1 & 0xffff0000u);
    }
    __syncthreads();
    SPEC_BUILD(0, 0, 0);
    __syncthreads();
    for (int cc = 0; cc < 48; ++cc) {
      int k = cc >> 1, ds = cc & 1;
      int kdbase = k * 256 + win * 64 + ds * 32;
      f16x8 af0 = *reinterpret_cast<const f16x8*>(
          A2 + (size_t)hrow * 6144 + kdbase + l4 * 8);
      f16x8 af1 = *reinterpret_cast<const f16x8*>(
          A2 + (size_t)(hrow + 16) * 6144 + kdbase + l4 * 8);
      if (cc < 47) {
        int k2 = (cc + 1) >> 1, ds2 = (cc + 1) & 1, bf2 = (cc + 1) & 1;
        SPEC_BUILD(k2, ds2, bf2);
      }
      int buf = cc & 1;
      #pragma unroll
      for (int fn = 0; fn < 4; ++fn) {
        f16x8 bf = *reinterpret_cast<const f16x8*>(&Bl[buf][fn * 16 + l15][l4 * 4]);
        acc[0][fn] = __builtin_amdgcn_mfma_f32_16x16x32_f16(af0, bf, acc[0][fn], 0, 0, 0);
        acc[1][fn] = __builtin_amdgcn_mfma_f32_16x16x32_f16(af1, bf, acc[1][fn], 0, 0, 0);
      }
      __syncthreads();
    }
  }

  float* Sff = reinterpret_cast<float*>(Sf);
  int b = l15 >> 1, ri = l15 & 1;
  #pragma unroll
  for (int fm = 0; fm < 2; ++fm)
    #pragma unroll
    for (int fn = 0; fn < 4; ++fn) {
      int r = min(r0 + fn, RR - 1);
      #pragma unroll
      for (int i = 0; i < 4; ++i) {
        int h = h0 + w * 32 + fm * 16 + l4 * 4 + i;
        Sff[((((size_t)(b * DD + h)) * RR + r) << 1) + ri] = acc[fm][fn][i];
      }
    }
}

// ---------------- fused MLP as two f16 MFMA GEMMs + residual ----------------
// Block: 64-column l-tile, 256 thr = 4 waves. S_lds[n][d] f16 XOR-swizzled
// (byte ^= (n&7)<<4); 4 h-chunks of 128: L1 MFMA -> gelu -> H_lds -> L2 MFMA.
__global__ void __launch_bounds__(256)
mlp_mfma(const float* __restrict__ S, const float* __restrict__ x,
         const unsigned short* __restrict__ W1h,   // [512][256] f16
         const float* __restrict__ b1,
         const unsigned short* __restrict__ W2h,   // [256][512] f16
         const float* __restrict__ b2,
         float* __restrict__ out) {
  __shared__ unsigned short S_lds[64 * 256];   // 32 KB, swizzled
  __shared__ unsigned short H_lds[64 * 128];   // 16 KB, swizzled
  char* Sb = reinterpret_cast<char*>(S_lds);
  char* Hb = reinterpret_cast<char*>(H_lds);

  int t = threadIdx.x;
  int lane = t & 63, w = t >> 6;
  int l15 = lane & 15, l4 = lane >> 4;
  int bb = blockIdx.x >> 5;
  int l0 = (blockIdx.x & 31) << 6;

  // ---- stage S -> S_lds[n][d] f16, swizzled. scalar loads, n = t&63 ----
  {
    int n = t & 63;
    int dbase = t >> 6;          // 0..3
    int n7s = (n & 7) << 4;
    const float* Sp = S + ((size_t)(bb * DD)) * LL + l0 + n;
    #pragma unroll 8
    for (int p = 0; p < 64; ++p) {
      int d = p * 4 + dbase;
      float v = Sp[(size_t)d * LL];
      *reinterpret_cast<unsigned short*>(Sb + n * 512 + ((2 * d) ^ n7s)) = f2h(v);
    }
  }

  f32x4 acc2[4][4];
  #pragma unroll
  for (int fm = 0; fm < 4; ++fm)
    #pragma unroll
    for (int fn = 0; fn < 4; ++fn) acc2[fm][fn] = (f32x4){0.f, 0.f, 0.f, 0.f};

  for (int ch = 0; ch < 4; ++ch) {
    __syncthreads();   // staging done (ch=0) / prev layer2 done reading H_lds
    // ---- layer 1: H[128h x 64n] for this chunk; wave owns 32 h ----
    f32x4 acc1[2][4];
    #pragma unroll
    for (int fm = 0; fm < 2; ++fm) {
      float4 b1v = *reinterpret_cast<const float4*>(
          b1 + ch * 128 + w * 32 + fm * 16 + l4 * 4);
      #pragma unroll
      for (int fn = 0; fn < 4; ++fn)
        acc1[fm][fn] = (f32x4){b1v.x, b1v.y, b1v.z, b1v.w};
    }
    #pragma unroll
    for (int ks = 0; ks < 8; ++ks) {
      f16x8 af0 = *reinterpret_cast<const f16x8*>(
          W1h + (size_t)(ch * 128 + w * 32 + l15) * 256 + ks * 32 + l4 * 8);
      f16x8 af1 = *reinterpret_cast<const f16x8*>(
          W1h + (size_t)(ch * 128 + w * 32 + 16 + l15) * 256 + ks * 32 + l4 * 8);
      #pragma unroll
      for (int fn = 0; fn < 4; ++fn) {
        int n = fn * 16 + l15;
        f16x8 bf = *reinterpret_cast<const f16x8*>(
            Sb + n * 512 + ((64 * ks + 16 * l4) ^ ((n & 7) << 4)));
        acc1[0][fn] = __builtin_amdgcn_mfma_f32_16x16x32_f16(af0, bf, acc1[0][fn], 0, 0, 0);
        acc1[1][fn] = __builtin_amdgcn_mfma_f32_16x16x32_f16(af1, bf, acc1[1][fn], 0, 0, 0);
      }
    }
    // ---- gelu -> H_lds[n][h] swizzled ----
    #pragma unroll
    for (int fm = 0; fm < 2; ++fm)
      #pragma unroll
      for (int fn = 0; fn < 4; ++fn) {
        unsigned short hv[4];
        #pragma unroll
        for (int i = 0; i < 4; ++i) {
          float v = acc1[fm][fn][i];
          hv[i] = f2h(0.5f * v * (1.f + erff(v * 0.70710678118654752f)));
        }
        int n = fn * 16 + l15;
        int hl2 = 2 * (w * 32 + fm * 16 + l4 * 4);
        *reinterpret_cast<uint2*>(Hb + n * 256 + (hl2 ^ ((n & 7) << 4))) =
            *reinterpret_cast<uint2*>(hv);
      }
    __syncthreads();
    // ---- layer 2 partial: out[256d x 64n] += W2[:, chunk] * H ----
    #pragma unroll
    for (int ks = 0; ks < 4; ++ks) {
      f16x8 bfv[4];
      #pragma unroll
      for (int fn = 0; fn < 4; ++fn) {
        int n = fn * 16 + l15;
        bfv[fn] = *reinterpret_cast<const f16x8*>(
            Hb + n * 256 + ((64 * ks + 16 * l4) ^ ((n & 7) << 4)));
      }
      #pragma unroll
      for (int fm = 0; fm < 4; ++fm) {
        f16x8 af = *reinterpret_cast<const f16x8*>(
            W2h + (size_t)(w * 64 + fm * 16 + l15) * 512 + ch * 128 + ks * 32 + l4 * 8);
        #pragma unroll
        for (int fn = 0; fn < 4; ++fn)
          acc2[fm][fn] = __builtin_amdgcn_mfma_f32_16x16x32_f16(af, bfv[fn], acc2[fm][fn], 0, 0, 0);
      }
    }
  }

  // ---- epilogue: out = x + b2 + acc2 ----
  #pragma unroll
  for (int fm = 0; fm < 4; ++fm) {
    float4 b2v = *reinterpret_cast<const float4*>(b2 + w * 64 + fm * 16 + l4 * 4);
    #pragma unroll
    for (int i = 0; i < 4; ++i) {
      int d = w * 64 + fm * 16 + l4 * 4 + i;
      const float* xr = x + ((size_t)(bb * DD + d)) * LL + l0;
      float* orow = out + ((size_t)(bb * DD + d)) * LL + l0;
      float bias = (i == 0) ? b2v.x : (i == 1) ? b2v.y : (i == 2) ? b2v.z : b2v.w;
      #pragma unroll
      for (int fn = 0; fn < 4; ++fn) {
        int n = fn * 16 + l15;
        orow[n] = xr[n] + bias + acc2[fm][fn][i];
      }
    }
  }
}

extern "C" void kernel_launch(void* const* d_in, const int* in_sizes, int n_in,
                              void* d_out, int out_size, void* d_ws, size_t ws_size,
                              hipStream_t stream) {
  const float* x      = (const float*)d_in[0];
  const float* Phi_re = (const float*)d_in[1];
  const float* Phi_im = (const float*)d_in[2];
  const float* Theta  = (const float*)d_in[3];
  const float* gamma  = (const float*)d_in[4];
  const float* beta   = (const float*)d_in[5];
  const float* W1     = (const float*)d_in[6];
  const float* b1     = (const float*)d_in[7];
  const float* W2     = (const float*)d_in[8];
  const float* b2     = (const float*)d_in[9];

  float* ws = (float*)d_ws;
  float*    z   = ws;                            // 4,194,304 f (reused for S)
  unsigned* Xf2 = (unsigned*)(ws + 4194304);     // 2,099,200 u32 (f16 pairs)
  float2*   Sf  = (float2*)(ws + 8392704);       // 2,099,200 float2
  unsigned* A2u = (unsigned*)(ws + 12591104);    // 786,432 u32 (f16 Theta)
  unsigned* W1h = (unsigned*)(ws + 14163968);    // 65,536 u32 (f16 W1)
  unsigned* W2h = (unsigned*)(ws + 14295040);    // 65,536 u32 (f16 W2)

  ln_kernel<<<dim3(BB * (LL / 64)), 256, 0, stream>>>(x, gamma, beta, z);
  theta_prep<<<dim3(KK * 256), 128, 0, stream>>>(Theta, A2u);
  w_prep<<<dim3(256), 256, 0, stream>>>(W1, W2, W1h, W2h);
  rfft_kernel<<<dim3(BB * DD), 256, 0, stream>>>(z, Xf2);
  spectral_mfma<<<dim3(257, 2), 256, 0, stream>>>(
      Xf2, (const unsigned short*)A2u, Phi_re, Phi_im, Sf);
  irfft_kernel<<<dim3(BB * DD), 256, 0, stream>>>(Sf, z);      // S -> z
  mlp_mfma<<<dim3(256), 256, 0, stream>>>(
      z, x, (const unsigned short*)W1h, b1, (const unsigned short*)W2h, b2,
      (float*)d_out);
}